// Round 2
// baseline (525.450 us; speedup 1.0000x reference)
//
#include <hip/hip_runtime.h>

#define PI_F 3.14159265358979323846f

typedef __attribute__((ext_vector_type(8))) short short8;
typedef __attribute__((ext_vector_type(4))) float floatx4;

__device__ __forceinline__ unsigned short f2bf(float x) {
  unsigned u = __builtin_bit_cast(unsigned, x);
  u += 0x7fffu + ((u >> 16) & 1u);
  return (unsigned short)(u >> 16);
}
__device__ __forceinline__ float bf2f(unsigned short s) {
  return __builtin_bit_cast(float, ((unsigned)s) << 16);
}

// ---------------------------------------------------------------------------
// K1: per-pixel MLP (118 -> 32 x4), h4 bf16 [16384][32].
// launch_bounds(128,1): min 1 wave/EU -> VGPR cap 512, no scratch spill.
// ---------------------------------------------------------------------------
__global__ __launch_bounds__(128, 1) void k_mlp(
    const float* __restrict__ W1, const float* __restrict__ b1,
    const float* __restrict__ W2, const float* __restrict__ b2,
    const float* __restrict__ W3, const float* __restrict__ b3,
    const float* __restrict__ W4, const float* __restrict__ b4,
    unsigned short* __restrict__ h4out)
{
  __shared__ __align__(16) float W1s[118 * 32];
  __shared__ __align__(16) float W2s[1024], W3s[1024], W4s[1024];
  __shared__ __align__(16) float bcs[32], b2s[32], b3s[32], b4s[32];
  const int tid = threadIdx.x;
  for (int i = tid; i < 118 * 32; i += 128) W1s[i] = W1[i];
  for (int i = tid; i < 1024; i += 128) { W2s[i] = W2[i]; W3s[i] = W3[i]; W4s[i] = W4[i]; }
  if (tid < 32) { b2s[tid] = b2[tid]; b3s[tid] = b3[tid]; b4s[tid] = b4[tid]; }
  __syncthreads();
  if (tid < 32) {
    float a = b1[tid];
    for (int i = 0; i < 25; ++i) {
      float fi = 1.0f + (float)i * (1.0f / 24.0f);
      float xs = cosf(5.0f * PI_F * fi);                 // scale_enc (scale = 2.0 both dims)
      a += xs * (W1s[(50 + i) * 32 + tid] + W1s[(75 + i) * 32 + tid]);
    }
    for (int j = 100; j < 118; ++j) a -= W1s[j * 32 + tid];  // kernel_enc == -1
    bcs[tid] = a;
  }
  __syncthreads();

  const int pix = blockIdx.x * 128 + tid;
  const int h = pix >> 7, w = pix & 127;
  float acc[32];
  #pragma unroll
  for (int u = 0; u < 32; ++u) acc[u] = bcs[u];
  const float ga = PI_F * (2.0f * (float)h * (1.0f / 127.0f) + 1.0f);
  const float gb = PI_F * (2.0f * (float)w * (1.0f / 127.0f) + 1.0f);
  for (int i = 0; i < 25; ++i) {
    float fi = 1.0f + (float)i * (1.0f / 24.0f);
    float xa = cosf(ga * fi);
    float xb = cosf(gb * fi);
    #pragma unroll
    for (int u = 0; u < 32; ++u)
      acc[u] += xa * W1s[i * 32 + u] + xb * W1s[(25 + i) * 32 + u];
  }
  float hv[32];
  auto layer = [&](const float* Wl, const float* bl) {
    #pragma unroll
    for (int u = 0; u < 32; ++u) hv[u] = fmaxf(acc[u], 0.0f);
    #pragma unroll
    for (int u = 0; u < 32; ++u) acc[u] = bl[u];
    #pragma unroll
    for (int j = 0; j < 32; ++j) {
      float xj = hv[j];
      #pragma unroll
      for (int u = 0; u < 32; ++u) acc[u] += xj * Wl[j * 32 + u];
    }
  };
  layer(W2s, b2s);
  layer(W3s, b3s);
  layer(W4s, b4s);
  unsigned short o[32];
  #pragma unroll
  for (int u = 0; u < 32; ++u) o[u] = f2bf(fmaxf(acc[u], 0.0f));
  #pragma unroll
  for (int u = 0; u < 32; u += 8) {
    short8 v;
    #pragma unroll
    for (int e = 0; e < 8; ++e) v[e] = (short)o[u + e];
    *(short8*)&h4out[pix * 32 + u] = v;
  }
}

// ---------------------------------------------------------------------------
// K1b: coalesced LDS-tiled transposes.
// blocks 0..35:  WoutT[tc][j]  <- Wout[j][tc]   (tiles of 64 tc x 32 j)
// blocks 36..51: WpT[f][c]     <- Wproj[c][f]   (tiles of 32 f x 64 c)
// ---------------------------------------------------------------------------
__global__ __launch_bounds__(256) void k_prep(
    const float* __restrict__ Wout, const float* __restrict__ Wproj,
    unsigned short* __restrict__ WoutT, unsigned short* __restrict__ WpT)
{
  __shared__ __align__(16) float tile[64][65];
  const int tid = threadIdx.x;
  const int bx = blockIdx.x;
  if (bx < 36) {
    const int tc0 = bx * 64;
    #pragma unroll
    for (int r = 0; r < 8; ++r) {
      int j = r * 4 + (tid >> 6);
      int c = tid & 63;
      tile[j][c] = Wout[j * 2304 + tc0 + c];       // coalesced 64-wide
    }
    __syncthreads();
    #pragma unroll
    for (int r = 0; r < 8; ++r) {
      int tc = r * 8 + (tid >> 5);
      int j = tid & 31;
      WoutT[(tc0 + tc) * 32 + j] = f2bf(tile[j][tc]);  // stride-65 col read: no conflicts
    }
  } else {
    const int b2 = bx - 36;
    const int f0 = (b2 >> 2) * 32, c0 = (b2 & 3) * 64;
    #pragma unroll
    for (int r = 0; r < 8; ++r) {
      int c = r * 8 + (tid >> 5);
      int f = tid & 31;
      tile[c][f] = Wproj[(c0 + c) * 128 + f0 + f]; // coalesced 32-wide
    }
    __syncthreads();
    #pragma unroll
    for (int r = 0; r < 8; ++r) {
      int f = r * 4 + (tid >> 6);
      int c = tid & 63;
      WpT[(f0 + f) * 256 + c0 + c] = f2bf(tile[c][f]);
    }
  }
}

// ---------------------------------------------------------------------------
// K2: fused ker-GEMM -> 3x3 tap-sum -> projection GEMM.
// v2: reg-staged prefetch (T14), fragment-linear LDS for W tiles, bf16 xup,
//     p_s aliased into WoutF. LDS = 75.3 KB -> 2 blocks/CU.
// ---------------------------------------------------------------------------
__global__ __launch_bounds__(256, 2) void k_main(
    const float* __restrict__ main_in,
    const float* __restrict__ b_out,
    const float* __restrict__ b_proj,
    const unsigned short* __restrict__ h4g,
    const unsigned short* __restrict__ WoutTg,
    const unsigned short* __restrict__ WpTg,
    float* __restrict__ out)
{
  // fragment-linear: slot s holds 8 ushorts for lane s&63 of n-tile s>>6
  __shared__ __align__(16) unsigned short WoutF[1152 * 8];        // 18432 B (aliased by p_s)
  __shared__ __align__(16) unsigned short wpF[512 * 8];           //  8192 B
  __shared__ __align__(16) unsigned short xup_s[4][3][34][36];    // 29376 B (bf16)
  __shared__ __align__(16) unsigned short ker_s[32][292];         // 18688 B
  __shared__ __align__(16) unsigned short bout_s[288];            //   576 B
  unsigned short (*p_s)[40] = (unsigned short (*)[40])WoutF;      // 128x40 = 10240 B <= 18432

  const int tid = threadIdx.x;
  const int lane = tid & 63;
  const int wv = tid >> 6;

  const int bx = blockIdx.x;
  const int sbx = (bx & 7) * 64 + (bx >> 3);      // XCD-contiguous tiles
  const int h = sbx >> 2;
  const int w0 = (sbx & 3) * 32;

  // A-fragment for GEMM-1 straight from global (chunk-invariant)
  const int mt1 = wv >> 1;
  const int ntb1 = (wv & 1) * 9;
  const short8 afrag = *(const short8*)&h4g[(h * 128 + w0 + mt1 * 16 + (lane & 15)) * 32 + 8 * (lane >> 4)];

  floatx4 acc2[2][8];
  #pragma unroll
  for (int i = 0; i < 2; ++i)
    #pragma unroll
    for (int n = 0; n < 8; ++n) acc2[i][n] = (floatx4){0.f, 0.f, 0.f, 0.f};

  const int tpix = tid >> 3;
  const int tclq = (tid & 7) * 4;
  unsigned short* xup_lin = &xup_s[0][0][0][0];

  // precompute xup staging maps (chunk-invariant): global base / lds ushort idx
  int gX[13], lX[13];
  #pragma unroll
  for (int it = 0; it < 13; ++it) {
    int u = tid + it * 256;
    int c4 = u & 7, s = u >> 3;
    int wcol = s % 34, s2 = s / 34, row = s2 % 3, b = s2 / 3;
    int hr = h + row - 1, wc = w0 + wcol - 1;
    bool inb = (u < 3264);
    bool ok = inb && hr >= 0 && hr < 128 && wc >= 0 && wc < 128;
    gX[it] = ok ? (((b * 64 + (hr >> 1)) * 64 + (wc >> 1)) * 256 + c4 * 4) : -1;
    lX[it] = inb ? (((b * 3 + row) * 34 + wcol) * 36 + c4 * 4) : -1;
  }

  short8 rW[5]; floatx4 rX[13]; short8 rP[2]; floatx4 rBo;

  auto issue_loads = [&](int c0) {
    #pragma unroll
    for (int it = 0; it < 5; ++it) {
      int u = tid + it * 256;
      if (u < 1152) {
        int nt = u >> 6, ln = u & 63;
        int t = nt >> 1, cl = (nt & 1) * 16 + (ln & 15), jb = ln >> 4;
        rW[it] = *(const short8*)&WoutTg[(t * 256 + c0 + cl) * 32 + jb * 8];
      }
    }
    #pragma unroll
    for (int it = 0; it < 13; ++it) {
      floatx4 v = (floatx4){0.f, 0.f, 0.f, 0.f};
      if (gX[it] >= 0) v = *(const floatx4*)&main_in[gX[it] + c0];
      rX[it] = v;
    }
    #pragma unroll
    for (int it = 0; it < 2; ++it) {
      int u = tid + it * 256;
      int nt = u >> 6, ln = u & 63;
      int f = nt * 16 + (ln & 15), cb = ln >> 4;
      rP[it] = *(const short8*)&WpTg[f * 256 + c0 + cb * 8];
    }
    if (tid < 72) rBo = *(const floatx4*)&b_out[(tid >> 3) * 256 + c0 + (tid & 7) * 4];
  };

  auto write_lds = [&]() {
    #pragma unroll
    for (int it = 0; it < 5; ++it) {
      int u = tid + it * 256;
      if (u < 1152) *(short8*)&WoutF[u * 8] = rW[it];
    }
    #pragma unroll
    for (int it = 0; it < 13; ++it) {
      if (lX[it] >= 0) {
        ushort4 pv;
        pv.x = f2bf(rX[it][0]); pv.y = f2bf(rX[it][1]);
        pv.z = f2bf(rX[it][2]); pv.w = f2bf(rX[it][3]);
        *(ushort4*)&xup_lin[lX[it]] = pv;
      }
    }
    #pragma unroll
    for (int it = 0; it < 2; ++it) {
      int u = tid + it * 256;
      *(short8*)&wpF[u * 8] = rP[it];
    }
    if (tid < 72) {
      ushort4 bv;
      bv.x = f2bf(rBo[0]); bv.y = f2bf(rBo[1]);
      bv.z = f2bf(rBo[2]); bv.w = f2bf(rBo[3]);
      *(ushort4*)&bout_s[(tid >> 3) * 32 + (tid & 7) * 4] = bv;
    }
  };

  issue_loads(0);   // prologue

  for (int ch = 0; ch < 8; ++ch) {
    __syncthreads();          // A: prev chunk's GEMM2 done reading p_s/wpF
    write_lds();              // implicit vmcnt wait on rX/rW/rP
    if (ch < 7) issue_loads((ch + 1) * 32);   // in flight across all compute
    __syncthreads();          // B

    // ---- GEMM-1: ker[pix][tc] = h4 . WoutT + b_out ----
    #pragma unroll
    for (int q = 0; q < 9; ++q) {
      int nt = ntb1 + q;
      short8 bfrag = *(const short8*)&WoutF[(nt * 64 + lane) * 8];
      floatx4 d = {0.f, 0.f, 0.f, 0.f};
      d = __builtin_amdgcn_mfma_f32_16x16x32_bf16(afrag, bfrag, d, 0, 0, 0);
      int tc = nt * 16 + (lane & 15);
      float bo = bf2f(bout_s[tc]);
      int prow = mt1 * 16 + (lane >> 4) * 4;
      #pragma unroll
      for (int r = 0; r < 4; ++r)
        ker_s[prow + r][tc] = f2bf(d[r] + bo);
    }
    __syncthreads();          // C

    // ---- tap-sum: p[b][pix][cl] = sum_t xup * ker ----
    {
      float pacc[4][4];
      #pragma unroll
      for (int b = 0; b < 4; ++b)
        #pragma unroll
        for (int qq = 0; qq < 4; ++qq) pacc[b][qq] = 0.f;
      #pragma unroll
      for (int t = 0; t < 9; ++t) {
        const int di = t / 3, dj = t % 3;
        ushort4 kv = *(const ushort4*)&ker_s[tpix][t * 32 + tclq];
        float k0 = bf2f(kv.x), k1 = bf2f(kv.y), k2 = bf2f(kv.z), k3 = bf2f(kv.w);
        #pragma unroll
        for (int b = 0; b < 4; ++b) {
          ushort4 xv = *(const ushort4*)&xup_s[b][di][tpix + dj][tclq];
          pacc[b][0] += k0 * bf2f(xv.x); pacc[b][1] += k1 * bf2f(xv.y);
          pacc[b][2] += k2 * bf2f(xv.z); pacc[b][3] += k3 * bf2f(xv.w);
        }
      }
      #pragma unroll
      for (int b = 0; b < 4; ++b) {
        ushort4 pv;
        pv.x = f2bf(pacc[b][0]); pv.y = f2bf(pacc[b][1]);
        pv.z = f2bf(pacc[b][2]); pv.w = f2bf(pacc[b][3]);
        *(ushort4*)&p_s[b * 32 + tpix][tclq] = pv;   // aliases WoutF (done being read)
      }
    }
    __syncthreads();          // D

    // ---- GEMM-2: out[bp][f] += p . wpT ----
    {
      short8 pa0 = *(const short8*)&p_s[(wv * 2 + 0) * 16 + (lane & 15)][8 * (lane >> 4)];
      short8 pa1 = *(const short8*)&p_s[(wv * 2 + 1) * 16 + (lane & 15)][8 * (lane >> 4)];
      #pragma unroll
      for (int nt = 0; nt < 8; ++nt) {
        short8 wb = *(const short8*)&wpF[(nt * 64 + lane) * 8];
        acc2[0][nt] = __builtin_amdgcn_mfma_f32_16x16x32_bf16(pa0, wb, acc2[0][nt], 0, 0, 0);
        acc2[1][nt] = __builtin_amdgcn_mfma_f32_16x16x32_bf16(pa1, wb, acc2[1][nt], 0, 0, 0);
      }
    }
  }

  // ---- epilogue ----
  #pragma unroll
  for (int nt = 0; nt < 8; ++nt) {
    int f = nt * 16 + (lane & 15);
    float bpj = b_proj[f];
    #pragma unroll
    for (int im = 0; im < 2; ++im) {
      int bp0 = (wv * 2 + im) * 16 + (lane >> 4) * 4;
      #pragma unroll
      for (int r = 0; r < 4; ++r) {
        int bp = bp0 + r;
        int b = bp >> 5, pix = bp & 31;
        out[((b * 128 + h) * 128 + (w0 + pix)) * 128 + f] = acc2[im][nt][r] + bpj;
      }
    }
  }
}

// ---------------------------------------------------------------------------
extern "C" void kernel_launch(void* const* d_in, const int* in_sizes, int n_in,
                              void* d_out, int out_size, void* d_ws, size_t ws_size,
                              hipStream_t stream) {
  const float* main_in = (const float*)d_in[0];
  const float* W1 = (const float*)d_in[2];
  const float* b1 = (const float*)d_in[3];
  const float* W2 = (const float*)d_in[4];
  const float* b2 = (const float*)d_in[5];
  const float* W3 = (const float*)d_in[6];
  const float* b3 = (const float*)d_in[7];
  const float* W4 = (const float*)d_in[8];
  const float* b4 = (const float*)d_in[9];
  const float* Wout = (const float*)d_in[10];
  const float* bout = (const float*)d_in[11];
  const float* Wproj = (const float*)d_in[12];
  const float* bproj = (const float*)d_in[13];
  float* outp = (float*)d_out;

  unsigned short* h4ws = (unsigned short*)d_ws;                       // 1,048,576 B
  unsigned short* WoutT = (unsigned short*)((char*)d_ws + 1048576);   //   147,456 B
  unsigned short* WpT = (unsigned short*)((char*)d_ws + 1048576 + 147456); // 65,536 B

  k_mlp<<<dim3(128), dim3(128), 0, stream>>>(W1, b1, W2, b2, W3, b3, W4, b4, h4ws);
  k_prep<<<dim3(52), dim3(256), 0, stream>>>(Wout, Wproj, WoutT, WpT);
  k_main<<<dim3(512), dim3(256), 0, stream>>>(main_in, bout, bproj, h4ws, WoutT, WpT, outp);
}

// Round 5
// 268.910 us; speedup vs baseline: 1.9540x; 1.9540x over previous
//
#include <hip/hip_runtime.h>

#define PI_F 3.14159265358979323846f

typedef __attribute__((ext_vector_type(8))) short short8;
typedef __attribute__((ext_vector_type(4))) float floatx4;

__device__ __forceinline__ unsigned short f2bf(float x) {
  unsigned u = __builtin_bit_cast(unsigned, x);
  u += 0x7fffu + ((u >> 16) & 1u);
  return (unsigned short)(u >> 16);
}
__device__ __forceinline__ float bf2f(unsigned short s) {
  return __builtin_bit_cast(float, ((unsigned)s) << 16);
}

// async global->LDS, 16B per lane. LDS ptr must be wave-uniform (base);
// HW writes base + lane*16. Generic->AS casts via integer round-trip:
// LDS aperture is 2^32-aligned on gfx9+, so generic LDS addr low 32 bits
// equals the LDS byte offset (CK pattern).
typedef __attribute__((address_space(1))) const unsigned int as1c_uint;
typedef __attribute__((address_space(3))) unsigned int as3_uint;
__device__ __forceinline__ void glds16(const void* g, void* l) {
  __builtin_amdgcn_global_load_lds(
      (as1c_uint*)(unsigned long long)g,
      (as3_uint*)(unsigned)(unsigned long long)l,
      16, 0, 0);
}

// ---------------------------------------------------------------------------
// K1 v3: MLP as MFMA. Block = one h row (128 pixels), 256 threads (4 waves),
// wave owns 32 pixels (2 m-tiles). Constant encoding dims folded into bias
// -> layer1 K=50 (pad 64). Layers 2-4 K=32. h ping-pong in LDS, rows are
// wave-private so no inter-layer barriers needed.
// ---------------------------------------------------------------------------
__global__ __launch_bounds__(256) void k_mlp(
    const float* __restrict__ W1, const float* __restrict__ b1,
    const float* __restrict__ W2, const float* __restrict__ b2,
    const float* __restrict__ W3, const float* __restrict__ b3,
    const float* __restrict__ W4, const float* __restrict__ b4,
    unsigned short* __restrict__ h4out)
{
  __shared__ __align__(16) unsigned short xb[128 * 72];     // [w][k<64], stride 72
  __shared__ __align__(16) unsigned short Wb1[32 * 72];     // [u][k<50]
  __shared__ __align__(16) unsigned short Wb2[32 * 40], Wb3[32 * 40], Wb4[32 * 40];
  __shared__ __align__(16) unsigned short hA[128 * 40], hB[128 * 40];
  __shared__ float bcs[32], b2s[32], b3s[32], b4s[32], xa_s[25];

  const int tid = threadIdx.x;
  const int h = blockIdx.x;
  const float ga = PI_F * (2.0f * (float)h * (1.0f / 127.0f) + 1.0f);

  // ---- stage weights (bf16, transposed to [out][in]) ----
  for (int i = tid; i < 32 * 72; i += 256) {                // i = k*32+u over k<72
    int k = i >> 5, u = i & 31;
    Wb1[u * 72 + k] = (k < 50) ? f2bf(W1[k * 32 + u]) : 0;
  }
  for (int i = tid; i < 1024; i += 256) {
    int j = i >> 5, u = i & 31;
    Wb2[u * 40 + j] = f2bf(W2[i]);
    Wb3[u * 40 + j] = f2bf(W3[i]);
    Wb4[u * 40 + j] = f2bf(W4[i]);
  }
  if (tid < 25) xa_s[tid] = cosf(ga * (1.0f + (float)tid * (1.0f / 24.0f)));
  if (tid >= 32 && tid < 64) { int u = tid - 32; b2s[u] = b2[u]; b3s[u] = b3[u]; b4s[u] = b4[u]; }
  if (tid >= 64 && tid < 96) {          // folded bias: b1 + const-encoding terms
    int u = tid - 64;
    float a = b1[u];
    for (int i = 0; i < 25; ++i) {
      float fi = 1.0f + (float)i * (1.0f / 24.0f);
      float xs = cosf(5.0f * PI_F * fi);                    // scale_enc (scale = 2.0)
      a += xs * (W1[(50 + i) * 32 + u] + W1[(75 + i) * 32 + u]);
    }
    for (int j = 100; j < 118; ++j) a -= W1[j * 32 + u];    // kernel_enc == -1
    bcs[u] = a;
  }
  __syncthreads();

  // ---- build x encodings [128 w][64 k] ----
  for (int i = tid; i < 8192; i += 256) {
    int w = i >> 6, k = i & 63;
    float v = 0.0f;
    if (k < 25) v = xa_s[k];
    else if (k < 50) {
      float gb = PI_F * (2.0f * (float)w * (1.0f / 127.0f) + 1.0f);
      v = cosf(gb * (1.0f + (float)(k - 25) * (1.0f / 24.0f)));
    }
    xb[w * 72 + k] = f2bf(v);
  }
  __syncthreads();

  const int lane = tid & 63, wv = tid >> 6;
  const int lr = lane & 15, lq = lane >> 4;

  // ---- layer 1 (K=64): xb @ Wb1 -> hA ----
  #pragma unroll
  for (int mt = 0; mt < 2; ++mt) {
    int prow = (wv * 2 + mt) * 16;
    short8 a0 = *(const short8*)&xb[(prow + lr) * 72 + 0 + lq * 8];
    short8 a1 = *(const short8*)&xb[(prow + lr) * 72 + 32 + lq * 8];
    #pragma unroll
    for (int nt = 0; nt < 2; ++nt) {
      short8 b0 = *(const short8*)&Wb1[(nt * 16 + lr) * 72 + 0 + lq * 8];
      short8 b1f = *(const short8*)&Wb1[(nt * 16 + lr) * 72 + 32 + lq * 8];
      floatx4 d = {0.f, 0.f, 0.f, 0.f};
      d = __builtin_amdgcn_mfma_f32_16x16x32_bf16(a0, b0, d, 0, 0, 0);
      d = __builtin_amdgcn_mfma_f32_16x16x32_bf16(a1, b1f, d, 0, 0, 0);
      float bv = bcs[nt * 16 + lr];
      #pragma unroll
      for (int r = 0; r < 4; ++r)
        hA[(prow + lq * 4 + r) * 40 + nt * 16 + lr] = f2bf(fmaxf(d[r] + bv, 0.f));
    }
  }

  // ---- layers 2,3 (K=32) ----
  auto doLayer = [&](const unsigned short* src, const unsigned short* Wt,
                     const float* bs, unsigned short* dst) {
    #pragma unroll
    for (int mt = 0; mt < 2; ++mt) {
      int prow = (wv * 2 + mt) * 16;
      short8 a = *(const short8*)&src[(prow + lr) * 40 + lq * 8];
      #pragma unroll
      for (int nt = 0; nt < 2; ++nt) {
        short8 b = *(const short8*)&Wt[(nt * 16 + lr) * 40 + lq * 8];
        floatx4 d = {0.f, 0.f, 0.f, 0.f};
        d = __builtin_amdgcn_mfma_f32_16x16x32_bf16(a, b, d, 0, 0, 0);
        float bv = bs[nt * 16 + lr];
        #pragma unroll
        for (int r = 0; r < 4; ++r)
          dst[(prow + lq * 4 + r) * 40 + nt * 16 + lr] = f2bf(fmaxf(d[r] + bv, 0.f));
      }
    }
  };
  doLayer(hA, Wb2, b2s, hB);
  doLayer(hB, Wb3, b3s, hA);

  // ---- layer 4 (K=32) -> global h4 ----
  #pragma unroll
  for (int mt = 0; mt < 2; ++mt) {
    int prow = (wv * 2 + mt) * 16;
    short8 a = *(const short8*)&hA[(prow + lr) * 40 + lq * 8];
    #pragma unroll
    for (int nt = 0; nt < 2; ++nt) {
      short8 b = *(const short8*)&Wb4[(nt * 16 + lr) * 40 + lq * 8];
      floatx4 d = {0.f, 0.f, 0.f, 0.f};
      d = __builtin_amdgcn_mfma_f32_16x16x32_bf16(a, b, d, 0, 0, 0);
      float bv = b4s[nt * 16 + lr];
      #pragma unroll
      for (int r = 0; r < 4; ++r)
        h4out[(h * 128 + prow + lq * 4 + r) * 32 + nt * 16 + lr] =
            f2bf(fmaxf(d[r] + bv, 0.f));
    }
  }
}

// ---------------------------------------------------------------------------
// K1b: coalesced LDS-tiled transposes.
// ---------------------------------------------------------------------------
__global__ __launch_bounds__(256) void k_prep(
    const float* __restrict__ Wout, const float* __restrict__ Wproj,
    unsigned short* __restrict__ WoutT, unsigned short* __restrict__ WpT)
{
  __shared__ __align__(16) float tile[64][65];
  const int tid = threadIdx.x;
  const int bx = blockIdx.x;
  if (bx < 36) {
    const int tc0 = bx * 64;
    #pragma unroll
    for (int r = 0; r < 8; ++r) {
      int j = r * 4 + (tid >> 6);
      int c = tid & 63;
      tile[j][c] = Wout[j * 2304 + tc0 + c];
    }
    __syncthreads();
    #pragma unroll
    for (int r = 0; r < 8; ++r) {
      int tc = r * 8 + (tid >> 5);
      int j = tid & 31;
      WoutT[(tc0 + tc) * 32 + j] = f2bf(tile[j][tc]);
    }
  } else {
    const int b2 = bx - 36;
    const int f0 = (b2 >> 2) * 32, c0 = (b2 & 3) * 64;
    #pragma unroll
    for (int r = 0; r < 8; ++r) {
      int c = r * 8 + (tid >> 5);
      int f = tid & 31;
      tile[c][f] = Wproj[(c0 + c) * 128 + f0 + f];
    }
    __syncthreads();
    #pragma unroll
    for (int r = 0; r < 8; ++r) {
      int f = r * 4 + (tid >> 6);
      int c = tid & 63;
      WpT[(f0 + f) * 256 + c0 + c] = f2bf(tile[c][f]);
    }
  }
}

// ---------------------------------------------------------------------------
// K2 v3: W tiles via global_load_lds (async, no VGPR); dedup'd raw input rows
// (2 rows x 18 cols f32) with scalarized staging regs; bout f32.
// LDS 78.4 KB -> 2 blocks/CU.
// ---------------------------------------------------------------------------
__global__ __launch_bounds__(256, 2) void k_main(
    const float* __restrict__ main_in,
    const float* __restrict__ b_out,
    const float* __restrict__ b_proj,
    const unsigned short* __restrict__ h4g,
    const unsigned short* __restrict__ WoutTg,
    const unsigned short* __restrict__ WpTg,
    float* __restrict__ out)
{
  __shared__ __align__(16) unsigned short WoutF[1152 * 8];   // 18432 B frag-linear
  __shared__ __align__(16) unsigned short wpF[512 * 8];      //  8192 B frag-linear
  __shared__ __align__(16) float raw_s[4 * 2 * 18 * 36];     // 20736 B
  __shared__ __align__(16) unsigned short ker_s[32][292];    // 18688 B
  __shared__ __align__(16) unsigned short p_s[128][44];      // 11264 B
  __shared__ __align__(16) float bout_s[288];                //  1152 B

  const int tid = threadIdx.x, lane = tid & 63, wv = tid >> 6;
  const int bx = blockIdx.x;
  const int sbx = (bx & 7) * 64 + (bx >> 3);   // XCD-contiguous h-rows
  const int h = sbx >> 2, w0 = (sbx & 3) * 32;
  const int r0 = (h - 1) >> 1;                 // first input row (may be -1)
  const int icol0 = (w0 - 1) >> 1;             // first input col (may be -1)

  const int mt1 = wv >> 1, ntb1 = (wv & 1) * 9;
  const short8 afrag = *(const short8*)
      &h4g[(h * 128 + w0 + mt1 * 16 + (lane & 15)) * 32 + 8 * (lane >> 4)];

  // ---- scalarized raw-staging maps (chunk-invariant) ----
  int gX0, gX1, gX2, gX3, gX4, lX0, lX1, lX2, lX3, lX4;
#define CALCMAP(N)                                                         \
  {                                                                        \
    int u = tid + N * 256;                                                 \
    bool valid = u < 1152;                                                 \
    int c4 = u & 7, s = u >> 3;                                            \
    int col = s % 18, s2 = s / 18, r = s2 & 1, b = s2 >> 1;                \
    int irow = r0 + r, icol = icol0 + col;                                 \
    bool ok = valid && irow >= 0 && irow < 64 && icol >= 0 && icol < 64;   \
    gX##N = ok ? (((b * 64 + irow) * 64 + icol) * 256 + c4 * 4) : -1;      \
    lX##N = valid ? (((b * 2 + r) * 18 + col) * 36 + c4 * 4) : -1;         \
  }
  CALCMAP(0) CALCMAP(1) CALCMAP(2) CALCMAP(3) CALCMAP(4)
#undef CALCMAP

  floatx4 rX0, rX1, rX2, rX3, rX4, rBo;
#define ISSUE1(N, c0)                                                      \
  {                                                                        \
    floatx4 v = {0.f, 0.f, 0.f, 0.f};                                      \
    if (gX##N >= 0) v = *(const floatx4*)&main_in[gX##N + (c0)];           \
    rX##N = v;                                                             \
  }
#define ISSUE_RAW(c0)                                                      \
  {                                                                        \
    ISSUE1(0, c0) ISSUE1(1, c0) ISSUE1(2, c0) ISSUE1(3, c0) ISSUE1(4, c0)  \
    if (tid < 72)                                                          \
      rBo = *(const floatx4*)&b_out[(tid >> 3) * 256 + (c0) + (tid & 7) * 4]; \
  }
#define WRITE_RAW()                                                        \
  {                                                                        \
    if (lX0 >= 0) *(floatx4*)&raw_s[lX0] = rX0;                            \
    if (lX1 >= 0) *(floatx4*)&raw_s[lX1] = rX1;                            \
    if (lX2 >= 0) *(floatx4*)&raw_s[lX2] = rX2;                            \
    if (lX3 >= 0) *(floatx4*)&raw_s[lX3] = rX3;                            \
    if (lX4 >= 0) *(floatx4*)&raw_s[lX4] = rX4;                            \
    if (tid < 72)                                                          \
      *(floatx4*)&bout_s[(tid >> 3) * 32 + (tid & 7) * 4] = rBo;           \
  }

  auto gldsW = [&](int c0) {
    #pragma unroll
    for (int it = 0; it < 5; ++it) {
      if (it == 4 && wv >= 2) continue;            // wave-uniform mask
      int nt = it * 4 + wv;
      int t = nt >> 1, cl = (nt & 1) * 16 + (lane & 15), jb = lane >> 4;
      glds16(&WoutTg[(t * 256 + c0 + cl) * 32 + jb * 8],
             &WoutF[(it * 256 + wv * 64) * 8]);
    }
  };
  auto gldsWp = [&](int c0) {
    #pragma unroll
    for (int it = 0; it < 2; ++it) {
      int nt = it * 4 + wv;
      int f = nt * 16 + (lane & 15), cb = lane >> 4;
      glds16(&WpTg[f * 256 + c0 + cb * 8], &wpF[(it * 256 + wv * 64) * 8]);
    }
  };

  floatx4 acc2[2][8];
  #pragma unroll
  for (int i = 0; i < 2; ++i)
    #pragma unroll
    for (int n = 0; n < 8; ++n) acc2[i][n] = (floatx4){0.f, 0.f, 0.f, 0.f};

  const int tpix = tid >> 3, tclq = (tid & 7) * 4;
  int rm0 = ((h - 1) >> 1) - r0, rm1 = (h >> 1) - r0, rm2 = ((h + 1) >> 1) - r0;
  int lc0 = ((w0 + tpix - 1) >> 1) - icol0;
  int lc1 = ((w0 + tpix) >> 1) - icol0;
  int lc2 = ((w0 + tpix + 1) >> 1) - icol0;
  const int rmv[3] = {rm0, rm1, rm2};
  const int lcv[3] = {lc0, lc1, lc2};

  ISSUE_RAW(0);
  gldsW(0); gldsWp(0);

  for (int ch = 0; ch < 8; ++ch) {
    const int c0n = (ch + 1) * 32;
    __syncthreads();                       // A: prev chunk fully consumed
    WRITE_RAW();                           // compiler waits rX as needed
    asm volatile("s_waitcnt vmcnt(0)" ::: "memory");   // drain glds of this chunk
    __builtin_amdgcn_sched_barrier(0);     // rule #18: pin the drain
    __syncthreads();                       // B: raw_s, WoutF, wpF, bout_s visible
    if (ch < 7) ISSUE_RAW(c0n);            // prefetch next raw into regs

    // ---- GEMM-1: ker[pix][tc] = h4 . WoutT + b_out ----
    #pragma unroll
    for (int q = 0; q < 9; ++q) {
      int nt = ntb1 + q;
      short8 bfrag = *(const short8*)&WoutF[(nt * 64 + lane) * 8];
      floatx4 d = {0.f, 0.f, 0.f, 0.f};
      d = __builtin_amdgcn_mfma_f32_16x16x32_bf16(afrag, bfrag, d, 0, 0, 0);
      int tc = nt * 16 + (lane & 15);
      float bo = bout_s[tc];
      int prow = mt1 * 16 + (lane >> 4) * 4;
      #pragma unroll
      for (int r = 0; r < 4; ++r)
        ker_s[prow + r][tc] = f2bf(d[r] + bo);
    }
    // wpF -> regs before C so its glds refill at C can't race
    short8 wb0 = *(const short8*)&wpF[(0 * 64 + lane) * 8];
    short8 wb1 = *(const short8*)&wpF[(1 * 64 + lane) * 8];
    short8 wb2 = *(const short8*)&wpF[(2 * 64 + lane) * 8];
    short8 wb3 = *(const short8*)&wpF[(3 * 64 + lane) * 8];
    short8 wb4 = *(const short8*)&wpF[(4 * 64 + lane) * 8];
    short8 wb5 = *(const short8*)&wpF[(5 * 64 + lane) * 8];
    short8 wb6 = *(const short8*)&wpF[(6 * 64 + lane) * 8];
    short8 wb7 = *(const short8*)&wpF[(7 * 64 + lane) * 8];
    __syncthreads();                       // C: GEMM1 + wpF reads complete
    if (ch < 7) { gldsW(c0n); gldsWp(c0n); }   // async refill during tap-sum/GEMM2

    // ---- tap-sum: p[b][pix][cl] = sum_t raw * ker ----
    {
      float pacc[4][4];
      #pragma unroll
      for (int b = 0; b < 4; ++b)
        #pragma unroll
        for (int qq = 0; qq < 4; ++qq) pacc[b][qq] = 0.f;
      #pragma unroll
      for (int t = 0; t < 9; ++t) {
        const int di = t / 3, dj = t % 3;
        ushort4 kv = *(const ushort4*)&ker_s[tpix][t * 32 + tclq];
        float k0 = bf2f(kv.x), k1 = bf2f(kv.y), k2 = bf2f(kv.z), k3 = bf2f(kv.w);
        const int ridx = ((rmv[di]) * 18 + lcv[dj]) * 36 + tclq;
        #pragma unroll
        for (int b = 0; b < 4; ++b) {
          floatx4 xv = *(const floatx4*)&raw_s[b * 2 * 18 * 36 + ridx];
          pacc[b][0] += k0 * xv[0]; pacc[b][1] += k1 * xv[1];
          pacc[b][2] += k2 * xv[2]; pacc[b][3] += k3 * xv[3];
        }
      }
      #pragma unroll
      for (int b = 0; b < 4; ++b) {
        ushort4 pv;
        pv.x = f2bf(pacc[b][0]); pv.y = f2bf(pacc[b][1]);
        pv.z = f2bf(pacc[b][2]); pv.w = f2bf(pacc[b][3]);
        *(ushort4*)&p_s[b * 32 + tpix][tclq] = pv;
      }
    }
    __syncthreads();                       // D

    // ---- GEMM-2: out[bp][f] += p . wpT ----
    {
      short8 pa0 = *(const short8*)&p_s[(wv * 2 + 0) * 16 + (lane & 15)][8 * (lane >> 4)];
      short8 pa1 = *(const short8*)&p_s[(wv * 2 + 1) * 16 + (lane & 15)][8 * (lane >> 4)];
      acc2[0][0] = __builtin_amdgcn_mfma_f32_16x16x32_bf16(pa0, wb0, acc2[0][0], 0, 0, 0);
      acc2[1][0] = __builtin_amdgcn_mfma_f32_16x16x32_bf16(pa1, wb0, acc2[1][0], 0, 0, 0);
      acc2[0][1] = __builtin_amdgcn_mfma_f32_16x16x32_bf16(pa0, wb1, acc2[0][1], 0, 0, 0);
      acc2[1][1] = __builtin_amdgcn_mfma_f32_16x16x32_bf16(pa1, wb1, acc2[1][1], 0, 0, 0);
      acc2[0][2] = __builtin_amdgcn_mfma_f32_16x16x32_bf16(pa0, wb2, acc2[0][2], 0, 0, 0);
      acc2[1][2] = __builtin_amdgcn_mfma_f32_16x16x32_bf16(pa1, wb2, acc2[1][2], 0, 0, 0);
      acc2[0][3] = __builtin_amdgcn_mfma_f32_16x16x32_bf16(pa0, wb3, acc2[0][3], 0, 0, 0);
      acc2[1][3] = __builtin_amdgcn_mfma_f32_16x16x32_bf16(pa1, wb3, acc2[1][3], 0, 0, 0);
      acc2[0][4] = __builtin_amdgcn_mfma_f32_16x16x32_bf16(pa0, wb4, acc2[0][4], 0, 0, 0);
      acc2[1][4] = __builtin_amdgcn_mfma_f32_16x16x32_bf16(pa1, wb4, acc2[1][4], 0, 0, 0);
      acc2[0][5] = __builtin_amdgcn_mfma_f32_16x16x32_bf16(pa0, wb5, acc2[0][5], 0, 0, 0);
      acc2[1][5] = __builtin_amdgcn_mfma_f32_16x16x32_bf16(pa1, wb5, acc2[1][5], 0, 0, 0);
      acc2[0][6] = __builtin_amdgcn_mfma_f32_16x16x32_bf16(pa0, wb6, acc2[0][6], 0, 0, 0);
      acc2[1][6] = __builtin_amdgcn_mfma_f32_16x16x32_bf16(pa1, wb6, acc2[1][6], 0, 0, 0);
      acc2[0][7] = __builtin_amdgcn_mfma_f32_16x16x32_bf16(pa0, wb7, acc2[0][7], 0, 0, 0);
      acc2[1][7] = __builtin_amdgcn_mfma_f32_16x16x32_bf16(pa1, wb7, acc2[1][7], 0, 0, 0);
    }
  }

  // ---- epilogue ----
  #pragma unroll
  for (int nt = 0; nt < 8; ++nt) {
    int f = nt * 16 + (lane & 15);
    float bpj = b_proj[f];
    #pragma unroll
    for (int im = 0; im < 2; ++im) {
      int bp0 = (wv * 2 + im) * 16 + (lane >> 4) * 4;
      #pragma unroll
      for (int r = 0; r < 4; ++r) {
        int bp = bp0 + r;
        int b = bp >> 5, pix = bp & 31;
        out[((b * 128 + h) * 128 + (w0 + pix)) * 128 + f] = acc2[im][nt][r] + bpj;
      }
    }
  }
#undef ISSUE1
#undef ISSUE_RAW
#undef WRITE_RAW
}

// ---------------------------------------------------------------------------
extern "C" void kernel_launch(void* const* d_in, const int* in_sizes, int n_in,
                              void* d_out, int out_size, void* d_ws, size_t ws_size,
                              hipStream_t stream) {
  const float* main_in = (const float*)d_in[0];
  const float* W1 = (const float*)d_in[2];
  const float* b1 = (const float*)d_in[3];
  const float* W2 = (const float*)d_in[4];
  const float* b2 = (const float*)d_in[5];
  const float* W3 = (const float*)d_in[6];
  const float* b3 = (const float*)d_in[7];
  const float* W4 = (const float*)d_in[8];
  const float* b4 = (const float*)d_in[9];
  const float* Wout = (const float*)d_in[10];
  const float* bout = (const float*)d_in[11];
  const float* Wproj = (const float*)d_in[12];
  const float* bproj = (const float*)d_in[13];
  float* outp = (float*)d_out;

  unsigned short* h4ws = (unsigned short*)d_ws;                       // 1,048,576 B
  unsigned short* WoutT = (unsigned short*)((char*)d_ws + 1048576);   //   147,456 B
  unsigned short* WpT = (unsigned short*)((char*)d_ws + 1048576 + 147456); // 65,536 B

  k_mlp<<<dim3(128), dim3(256), 0, stream>>>(W1, b1, W2, b2, W3, b3, W4, b4, h4ws);
  k_prep<<<dim3(52), dim3(256), 0, stream>>>(Wout, Wproj, WoutT, WpT);
  k_main<<<dim3(512), dim3(256), 0, stream>>>(main_in, bout, bproj, h4ws, WoutT, WpT, outp);
}